// Round 16
// baseline (72.145 us; speedup 1.0000x reference)
//
#include <hip/hip_runtime.h>
#include <math.h>

#define NN 8192      // nodes
#define FH 128       // hidden
#define NC 16        // clusters
#define HP 132       // padded LDS row
#define CHUNK 16     // nodes per block in node phase (512 blocks -> 2/CU)

// ---------------- workspace layout (floats) ----------------
#define WS_CNT   0          // [8192]   zeroed by k_zero_cnt
#define WS_AGG4  8192       // [32768]  zeroed by k_degree
// accumulator region zeroed by k_edge_agg (blocks 0-22):
#define WS_ORAW  40960      // 8 x 2048 replicas
#define WS_SS    57344      // 8 x 256 replicas
#define WS_CA    59392      // 16 x 16
#define WS_CS    59648      // 16 x 16
#define WS_OADJ  59904      // 16 x 256 replicas
#define WS_END   64000
#define WS_ACC_BEGIN_F4 10240   // 40960/4
#define WS_ACC_COUNT_F4 5760    // (64000-40960)/4

// ---------------- K1: zero cnt only ----------------
__global__ __launch_bounds__(256) void k_zero_cnt(float4* __restrict__ ws) {
    int i = blockIdx.x * blockDim.x + threadIdx.x;   // 8 blocks
    if (i < NN / 4) ws[i] = make_float4(0.f, 0.f, 0.f, 0.f);
}

// ---------------- K2: in-degree (1 edge/thread, 512 blocks) + zero agg4 ----------------
__global__ __launch_bounds__(256) void k_degree(const int* __restrict__ ei,
                                                float* __restrict__ ws, int E) {
    int t = threadIdx.x, b = blockIdx.x;             // 512 blocks
    if (t < 16)   // zero agg4: 512 blocks x 16 f4 = 32768 floats
        reinterpret_cast<float4*>(ws)[NN / 4 + b * 16 + t] =
            make_float4(0.f, 0.f, 0.f, 0.f);
    int e = b * 256 + t;
    if (e < E) atomicAdd(&ws[WS_CNT + ei[E + e]], 1.0f);
}

// ---------------- K3: agg4 scatter (1 edge/thread, 512 blocks) + zero accumulators ----------------
__global__ __launch_bounds__(256) void k_edge_agg(const int* __restrict__ ei,
                                                  const float* __restrict__ x,
                                                  float* __restrict__ ws, int E) {
    int t = threadIdx.x, b = blockIdx.x;             // 512 blocks
    if (b < 23) {   // zero oraw/ss/ca/cs/oadj region (5760 f4)
        int i = b * 256 + t;
        if (i < WS_ACC_COUNT_F4)
            reinterpret_cast<float4*>(ws)[WS_ACC_BEGIN_F4 + i] =
                make_float4(0.f, 0.f, 0.f, 0.f);
    }
    int e = b * 256 + t;
    if (e >= E) return;
    int s = ei[e], d = ei[E + e];
    float di = rsqrtf(ws[WS_CNT + s] + 1.0f);
    float4 xv = reinterpret_cast<const float4*>(x)[s];
    float* agg4 = ws + WS_AGG4;
    atomicAdd(&agg4[d * 4 + 0], di * xv.x);
    atomicAdd(&agg4[d * 4 + 1], di * xv.y);
    atomicAdd(&agg4[d * 4 + 2], di * xv.z);
    atomicAdd(&agg4[d * 4 + 3], di * xv.w);
}

// ---------------- K4: fused node pipeline (16 nodes/block, 512 blocks) ----------------
__global__ __launch_bounds__(256) void k_node(const float* __restrict__ x,
                                              const float* __restrict__ W1,
                                              const float* __restrict__ b1,
                                              const float* __restrict__ Wp,
                                              const float* __restrict__ bp,
                                              float* __restrict__ ws,
                                              float* __restrict__ s_out) {
    float* cnt  = ws + WS_CNT;
    float* agg4 = ws + WS_AGG4;
    float* oraw = ws + WS_ORAW;
    float* ssb  = ws + WS_SS;
    float* cab  = ws + WS_CA;
    float* csb  = ws + WS_CS;

    __shared__ float h_lds[CHUNK][HP];     // 8.25 KB
    __shared__ float wpT[NC * HP];         // 8.25 KB
    __shared__ float s_lds[CHUNK][NC];     // 1 KB
    __shared__ float z_lds[CHUNK][4];
    __shared__ float c_lds[CHUNK];
    int t = threadIdx.x;
    int b = blockIdx.x;
    int base = b * CHUNK;

    #pragma unroll
    for (int r = 0; r < 8; ++r) {
        int idx = r * 256 + t;             // = f*16 + c
        wpT[(idx & 15) * HP + (idx >> 4)] = Wp[idx];
    }
    if (t < CHUNK) {
        float4 a  = reinterpret_cast<const float4*>(agg4)[base + t];
        float4 xv = reinterpret_cast<const float4*>(x)[base + t];
        float cn = cnt[base + t];
        c_lds[t] = cn;
        float di = rsqrtf(cn + 1.0f);
        z_lds[t][0] = di * fmaf(xv.x, di, a.x);
        z_lds[t][1] = di * fmaf(xv.y, di, a.y);
        z_lds[t][2] = di * fmaf(xv.z, di, a.z);
        z_lds[t][3] = di * fmaf(xv.w, di, a.w);
    }
    __syncthreads();

    int f = t & 127;
    {
        float w0 = W1[f], w1 = W1[128 + f], w2 = W1[256 + f], w3 = W1[384 + f];
        float bb = b1[f];
        int n0 = t >> 7;
        #pragma unroll
        for (int r = 0; r < 8; ++r) {
            int n = n0 + r * 2;
            float v = fmaf(z_lds[n][0], w0, bb);
            v = fmaf(z_lds[n][1], w1, v);
            v = fmaf(z_lds[n][2], w2, v);
            v = fmaf(z_lds[n][3], w3, v);
            h_lds[n][f] = fmaxf(v, 0.0f);
        }
    }
    __syncthreads();

    int c = t & 15, g = t >> 4;
    {
        int n = g;                         // 16 groups cover 16 nodes in one pass
        const float4* wrow = reinterpret_cast<const float4*>(&wpT[c * HP]);
        const float4* hrow = reinterpret_cast<const float4*>(&h_lds[n][0]);
        float logit = bp[c];
        #pragma unroll 8
        for (int q = 0; q < 32; ++q) {
            float4 hv = hrow[q];
            float4 wv = wrow[q];
            logit = fmaf(hv.x, wv.x, logit);
            logit = fmaf(hv.y, wv.y, logit);
            logit = fmaf(hv.z, wv.z, logit);
            logit = fmaf(hv.w, wv.w, logit);
        }
        float m = logit;
        #pragma unroll
        for (int o = 8; o; o >>= 1) m = fmaxf(m, __shfl_xor(m, o, 16));
        float ex = expf(logit - m);
        float sum = ex;
        #pragma unroll
        for (int o = 8; o; o >>= 1) sum += __shfl_xor(sum, o, 16);
        float sv = ex / sum;
        s_lds[n][c] = sv;
        s_out[(base + n) * NC + c] = sv;   // single copy (d_out); k_adj gathers here
    }
    __syncthreads();

    float acc[8] = {0, 0, 0, 0, 0, 0, 0, 0};
    float acc_ss = 0.0f, acc_ca = 0.0f, acc_cs = 0.0f;
    int ch = t >> 7;
    int cS = t >> 4, kS = t & 15;
    #pragma unroll
    for (int i = 0; i < CHUNK; ++i) {
        float hv = h_lds[i][f];
        const float4* sv = reinterpret_cast<const float4*>(&s_lds[i][0]);
        float4 sa = sv[ch * 2], sb = sv[ch * 2 + 1];
        acc[0] = fmaf(sa.x, hv, acc[0]);
        acc[1] = fmaf(sa.y, hv, acc[1]);
        acc[2] = fmaf(sa.z, hv, acc[2]);
        acc[3] = fmaf(sa.w, hv, acc[3]);
        acc[4] = fmaf(sb.x, hv, acc[4]);
        acc[5] = fmaf(sb.y, hv, acc[5]);
        acc[6] = fmaf(sb.z, hv, acc[6]);
        acc[7] = fmaf(sb.w, hv, acc[7]);
        acc_ss = fmaf(s_lds[i][cS], s_lds[i][kS], acc_ss);
    }
    if (t < NC) {
        #pragma unroll
        for (int i = 0; i < CHUNK; ++i) {
            acc_ca = fmaf(s_lds[i][t], c_lds[i], acc_ca);
            acc_cs += s_lds[i][t];
        }
    }
    int rep = b & 7;                       // 8 replicas (512 blocks)
    #pragma unroll
    for (int j = 0; j < 8; ++j)
        atomicAdd(&oraw[rep * 2048 + (ch * 8 + j) * FH + f], acc[j]);
    atomicAdd(&ssb[rep * 256 + cS * NC + kS], acc_ss);
    if (t < NC) {
        int rep16 = b & 15;
        atomicAdd(&cab[rep16 * NC + t], acc_ca);
        atomicAdd(&csb[rep16 * NC + t], acc_cs);
    }
}

// ---------------- K5: out_adj (batched gathers, intra-wave shfl reduce) ----------------
#define ADJ_BLOCKS 1024
__global__ __launch_bounds__(256) void k_adj(const int* __restrict__ ei,
                                             const float* __restrict__ s,
                                             float* __restrict__ ws, int E) {
    float* oadj = ws + WS_OADJ;

    __shared__ float red[4 * 256];         // 4 KB

    int t = threadIdx.x;
    int b = blockIdx.x;
    int q = t & 15;                        // cluster lane (c)
    int seg = (t >> 4) & 3;                // 16-lane segment within wave
    int wave = (b * 256 + t) >> 6;         // global wave id; wave handles 32 edges

    float acc[16];
    #pragma unroll
    for (int k = 0; k < 16; ++k) acc[k] = 0.0f;

    {
        int wbase = wave * 32;
        int e0 = wbase + q, e1 = wbase + 16 + q;
        int es0 = (e0 < E) ? ei[e0] : 0;
        int ed0 = (e0 < E) ? ei[E + e0] : 0;
        int es1 = (e1 < E) ? ei[e1] : 0;
        int ed1 = (e1 < E) ? ei[E + e1] : 0;

        float av[8], bv[8];
        #pragma unroll
        for (int i = 0; i < 4; ++i) {
            int m = seg * 4 + i;
            int sN0 = __shfl(es0, m, 16), dN0 = __shfl(ed0, m, 16);
            int sN1 = __shfl(es1, m, 16), dN1 = __shfl(ed1, m, 16);
            av[i]     = s[sN0 * NC + q];
            bv[i]     = ((wbase + m) < E) ? s[dN0 * NC + q] : 0.0f;
            av[4 + i] = s[sN1 * NC + q];
            bv[4 + i] = ((wbase + 16 + m) < E) ? s[dN1 * NC + q] : 0.0f;
        }
        #pragma unroll
        for (int i = 0; i < 8; ++i) {
            #pragma unroll
            for (int k = 0; k < 16; ++k)
                acc[k] = fmaf(__shfl(av[i], k, 16), bv[i], acc[k]);
        }
    }

    #pragma unroll
    for (int k = 0; k < 16; ++k) {
        acc[k] += __shfl_xor(acc[k], 16, 64);
        acc[k] += __shfl_xor(acc[k], 32, 64);
    }
    int wv = t >> 6, lane = t & 63;
    if (lane < 16) {
        #pragma unroll
        for (int k = 0; k < 16; ++k) red[wv * 256 + k * 16 + lane] = acc[k];
    }
    __syncthreads();
    {
        int i = t;                         // kk*16+cc
        float v = red[i] + red[256 + i] + red[512 + i] + red[768 + i];
        atomicAdd(&oadj[(b & 15) * 256 + i], v);
    }
}

// ---------------- K6: sync-free epilogue (1 block, 4 waves, no LDS) ----------------
__device__ __forceinline__ float selu_f(float x) {
    const float a = 1.6732632423543772f, sc = 1.0507009873554805f;
    return sc * (x > 0.0f ? x : a * (expf(x) - 1.0f));
}

__global__ __launch_bounds__(256) void k_final(float* __restrict__ ws,
                                               float* __restrict__ d_out, float Ef) {
    float* oraw = ws + WS_ORAW;
    float* ssb  = ws + WS_SS;
    float* cab  = ws + WS_CA;
    float* csb  = ws + WS_CS;
    float* oadj = ws + WS_OADJ;
    int t = threadIdx.x;
    int lane = t & 63, w = t >> 6;

    if (w == 0) {
        float tot[4];
        float fr2 = 0.f;
        #pragma unroll
        for (int j = 0; j < 4; ++j) {
            int i = lane + j * 64;
            float v = 0.f;
            #pragma unroll
            for (int r = 0; r < 8; ++r) v += ssb[r * 256 + i];
            tot[j] = v;
            fr2 += v * v;
        }
        #pragma unroll
        for (int o = 32; o; o >>= 1) fr2 += __shfl_xor(fr2, o, 64);
        float fro = sqrtf(fr2);
        float o2 = 0.f;
        #pragma unroll
        for (int j = 0; j < 4; ++j) {
            int i = lane + j * 64;
            float d = tot[j] / fro - ((i % 17 == 0) ? 0.25f : 0.f);
            o2 += d * d;
        }
        #pragma unroll
        for (int o = 32; o; o >>= 1) o2 += __shfl_xor(o2, o, 64);
        float ortho = sqrtf(o2);

        float tv = 0.f, ca = 0.f, cs = 0.f;
        if (lane < 16) {
            #pragma unroll
            for (int r = 0; r < 16; ++r) tv += oadj[r * 256 + lane * 17];
            #pragma unroll
            for (int r = 0; r < 16; ++r) { ca += cab[r * 16 + lane]; cs += csb[r * 16 + lane]; }
        }
        float tr = tv, can = ca * ca, csn = cs * cs;
        #pragma unroll
        for (int o = 32; o; o >>= 1) {
            tr  += __shfl_xor(tr, o, 64);
            can += __shfl_xor(can, o, 64);
            csn += __shfl_xor(csn, o, 64);
        }
        float spectral = -(tr - can / Ef) / Ef;
        float cluster = sqrtf(csn) / (float)NN * 4.0f - 1.0f;
        if (lane == 0) d_out[NC * FH] = spectral + ortho + cluster;
    }

    #pragma unroll
    for (int rr = 0; rr < 4; ++rr) {
        int cR = w + rr * 4;
        int c0 = lane * 2;
        float va = 0.f, vb = 0.f;
        #pragma unroll
        for (int r = 0; r < 8; ++r) {
            float2 vv = *reinterpret_cast<const float2*>(&oraw[r * 2048 + cR * FH + c0]);
            va += vv.x;
            vb += vv.y;
        }
        va = selu_f(va);
        vb = selu_f(vb);
        float mx = fmaxf(va, vb);
        #pragma unroll
        for (int o = 32; o; o >>= 1) mx = fmaxf(mx, __shfl_xor(mx, o, 64));
        float sm = expf(va - mx) + expf(vb - mx);
        #pragma unroll
        for (int o = 32; o; o >>= 1) sm += __shfl_xor(sm, o, 64);
        float ls = mx + logf(sm);
        d_out[cR * FH + c0]     = va - ls;
        d_out[cR * FH + c0 + 1] = vb - ls;
    }
}

extern "C" void kernel_launch(void* const* d_in, const int* in_sizes, int n_in,
                              void* d_out, int out_size, void* d_ws, size_t ws_size,
                              hipStream_t stream) {
    const float* x  = (const float*)d_in[0];
    const float* W1 = (const float*)d_in[1];
    const float* b1 = (const float*)d_in[2];
    const float* Wp = (const float*)d_in[3];
    const float* bp = (const float*)d_in[4];
    const int*   ei = (const int*)d_in[5];
    int E = in_sizes[5] / 2;

    float* ws  = (float*)d_ws;
    float* out = (float*)d_out;           // [0..2047] log_softmax, [2048] loss
    float* s   = out + NC * FH + 1;       // [2049..] assignments (8192 x 16)

    k_zero_cnt<<<8, 256, 0, stream>>>((float4*)d_ws);
    k_degree  <<<(E + 255) / 256, 256, 0, stream>>>(ei, ws, E);
    k_edge_agg<<<(E + 255) / 256, 256, 0, stream>>>(ei, x, ws, E);
    k_node    <<<NN / CHUNK, 256, 0, stream>>>(x, W1, b1, Wp, bp, ws, s);
    k_adj     <<<ADJ_BLOCKS, 256, 0, stream>>>(ei, s, ws, E);
    k_final   <<<1, 256, 0, stream>>>(ws, out, (float)E);
}

// Round 17
// 67.800 us; speedup vs baseline: 1.0641x; 1.0641x over previous
//
#include <hip/hip_runtime.h>
#include <math.h>

#define NN 8192      // nodes
#define FH 128       // hidden
#define NC 16        // clusters
#define HP 132       // padded LDS row
#define CHUNK 32     // nodes per block in node phase (256 blocks)

// ---------------- workspace layout (floats) ----------------
#define WS_CNT   0          // [8192]   zeroed by k_zero_cnt
#define WS_AGG4  8192       // [32768]  zeroed by k_degree
// accumulator region zeroed by k_edge_agg (blocks 0-9):
#define WS_ORAW  40960      // 4 x 2048 replicas
#define WS_SS    49152      // 4 x 256 replicas
#define WS_CA    50176      // 16 x 16
#define WS_CS    50432      // 16 x 16
#define WS_TR    50688      // 16 replicas spread 32 floats (128B) apart
#define WS_END   51200
#define WS_ACC_BEGIN_F4 10240   // 40960/4
#define WS_ACC_COUNT_F4 2560    // (51200-40960)/4

// ---------------- K1: zero cnt only ----------------
__global__ __launch_bounds__(256) void k_zero_cnt(float4* __restrict__ ws) {
    int i = blockIdx.x * blockDim.x + threadIdx.x;   // 8 blocks
    if (i < NN / 4) ws[i] = make_float4(0.f, 0.f, 0.f, 0.f);
}

// ---------------- K2: in-degree (1 edge/thread, 512 blocks) + zero agg4 ----------------
__global__ __launch_bounds__(256) void k_degree(const int* __restrict__ ei,
                                                float* __restrict__ ws, int E) {
    int t = threadIdx.x, b = blockIdx.x;             // 512 blocks
    if (t < 16)   // zero agg4: 512 blocks x 16 f4 = 32768 floats
        reinterpret_cast<float4*>(ws)[NN / 4 + b * 16 + t] =
            make_float4(0.f, 0.f, 0.f, 0.f);
    int e = b * 256 + t;
    if (e < E) atomicAdd(&ws[WS_CNT + ei[E + e]], 1.0f);
}

// ---------------- K3: agg4 scatter (1 edge/thread, 512 blocks) + zero accumulators ----------------
__global__ __launch_bounds__(256) void k_edge_agg(const int* __restrict__ ei,
                                                  const float* __restrict__ x,
                                                  float* __restrict__ ws, int E) {
    int t = threadIdx.x, b = blockIdx.x;             // 512 blocks
    if (b < 10) {   // zero oraw/ss/ca/cs/tr region (2560 f4)
        reinterpret_cast<float4*>(ws)[WS_ACC_BEGIN_F4 + b * 256 + t] =
            make_float4(0.f, 0.f, 0.f, 0.f);
    }
    int e = b * 256 + t;
    if (e >= E) return;
    int s = ei[e], d = ei[E + e];
    float di = rsqrtf(ws[WS_CNT + s] + 1.0f);
    float4 xv = reinterpret_cast<const float4*>(x)[s];
    float* agg4 = ws + WS_AGG4;
    atomicAdd(&agg4[d * 4 + 0], di * xv.x);
    atomicAdd(&agg4[d * 4 + 1], di * xv.y);
    atomicAdd(&agg4[d * 4 + 2], di * xv.z);
    atomicAdd(&agg4[d * 4 + 3], di * xv.w);
}

// ---------------- K4: fused node pipeline (32 nodes/block, 256 blocks) ----------------
__global__ __launch_bounds__(256) void k_node(const float* __restrict__ x,
                                              const float* __restrict__ W1,
                                              const float* __restrict__ b1,
                                              const float* __restrict__ Wp,
                                              const float* __restrict__ bp,
                                              float* __restrict__ ws,
                                              float* __restrict__ s_out) {
    float* cnt  = ws + WS_CNT;
    float* agg4 = ws + WS_AGG4;
    float* oraw = ws + WS_ORAW;
    float* ssb  = ws + WS_SS;
    float* cab  = ws + WS_CA;
    float* csb  = ws + WS_CS;

    __shared__ float h_lds[CHUNK][HP];
    __shared__ float wpT[NC * HP];
    __shared__ float s_lds[CHUNK][NC];
    __shared__ float z_lds[CHUNK][4];
    __shared__ float c_lds[CHUNK];
    int t = threadIdx.x;
    int b = blockIdx.x;
    int base = b * CHUNK;

    #pragma unroll
    for (int r = 0; r < 8; ++r) {
        int idx = r * 256 + t;             // = f*16 + c
        wpT[(idx & 15) * HP + (idx >> 4)] = Wp[idx];
    }
    if (t < CHUNK) {
        float4 a  = reinterpret_cast<const float4*>(agg4)[base + t];
        float4 xv = reinterpret_cast<const float4*>(x)[base + t];
        float cn = cnt[base + t];
        c_lds[t] = cn;
        float di = rsqrtf(cn + 1.0f);
        z_lds[t][0] = di * fmaf(xv.x, di, a.x);
        z_lds[t][1] = di * fmaf(xv.y, di, a.y);
        z_lds[t][2] = di * fmaf(xv.z, di, a.z);
        z_lds[t][3] = di * fmaf(xv.w, di, a.w);
    }
    __syncthreads();

    int f = t & 127;
    {
        float w0 = W1[f], w1 = W1[128 + f], w2 = W1[256 + f], w3 = W1[384 + f];
        float bb = b1[f];
        int n0 = t >> 7;
        #pragma unroll
        for (int r = 0; r < 16; ++r) {
            int n = n0 + r * 2;
            float v = fmaf(z_lds[n][0], w0, bb);
            v = fmaf(z_lds[n][1], w1, v);
            v = fmaf(z_lds[n][2], w2, v);
            v = fmaf(z_lds[n][3], w3, v);
            h_lds[n][f] = fmaxf(v, 0.0f);
        }
    }
    __syncthreads();

    int c = t & 15, g = t >> 4;
    const float4* wrow = reinterpret_cast<const float4*>(&wpT[c * HP]);
    #pragma unroll
    for (int pass = 0; pass < 2; ++pass) {
        int n = pass * 16 + g;
        const float4* hrow = reinterpret_cast<const float4*>(&h_lds[n][0]);
        float logit = bp[c];
        #pragma unroll 8
        for (int q = 0; q < 32; ++q) {
            float4 hv = hrow[q];
            float4 wv = wrow[q];
            logit = fmaf(hv.x, wv.x, logit);
            logit = fmaf(hv.y, wv.y, logit);
            logit = fmaf(hv.z, wv.z, logit);
            logit = fmaf(hv.w, wv.w, logit);
        }
        float m = logit;
        #pragma unroll
        for (int o = 8; o; o >>= 1) m = fmaxf(m, __shfl_xor(m, o, 16));
        float ex = expf(logit - m);
        float sum = ex;
        #pragma unroll
        for (int o = 8; o; o >>= 1) sum += __shfl_xor(sum, o, 16);
        float sv = ex / sum;
        s_lds[n][c] = sv;
        s_out[(base + n) * NC + c] = sv;   // single copy (d_out); k_adj gathers here
    }
    __syncthreads();

    float acc[8] = {0, 0, 0, 0, 0, 0, 0, 0};
    float acc_ss = 0.0f, acc_ca = 0.0f, acc_cs = 0.0f;
    int ch = t >> 7;
    int cS = t >> 4, kS = t & 15;
    #pragma unroll
    for (int i = 0; i < CHUNK; ++i) {
        float hv = h_lds[i][f];
        const float4* sv = reinterpret_cast<const float4*>(&s_lds[i][0]);
        float4 sa = sv[ch * 2], sb = sv[ch * 2 + 1];
        acc[0] = fmaf(sa.x, hv, acc[0]);
        acc[1] = fmaf(sa.y, hv, acc[1]);
        acc[2] = fmaf(sa.z, hv, acc[2]);
        acc[3] = fmaf(sa.w, hv, acc[3]);
        acc[4] = fmaf(sb.x, hv, acc[4]);
        acc[5] = fmaf(sb.y, hv, acc[5]);
        acc[6] = fmaf(sb.z, hv, acc[6]);
        acc[7] = fmaf(sb.w, hv, acc[7]);
        acc_ss = fmaf(s_lds[i][cS], s_lds[i][kS], acc_ss);
    }
    if (t < NC) {
        #pragma unroll
        for (int i = 0; i < CHUNK; ++i) {
            acc_ca = fmaf(s_lds[i][t], c_lds[i], acc_ca);
            acc_cs += s_lds[i][t];
        }
    }
    int rep = b & 3;
    #pragma unroll
    for (int j = 0; j < 8; ++j)
        atomicAdd(&oraw[rep * 2048 + (ch * 8 + j) * FH + f], acc[j]);
    atomicAdd(&ssb[rep * 256 + cS * NC + kS], acc_ss);
    if (t < NC) {
        int rep16 = b & 15;
        atomicAdd(&cab[rep16 * NC + t], acc_ca);
        atomicAdd(&csb[rep16 * NC + t], acc_cs);
    }
}

// ---------------- K5: TRACE-only adjacency: tr += <s[src], s[dst]> per edge ----------------
// (full 16x16 out_adj is dead code in the reference -- only its trace feeds spectral)
#define ADJ_BLOCKS 1024
__global__ __launch_bounds__(256) void k_adj(const int* __restrict__ ei,
                                             const float* __restrict__ s,
                                             float* __restrict__ ws, int E) {
    float* trb = ws + WS_TR;

    int t = threadIdx.x;
    int b = blockIdx.x;
    int q = t & 15;                        // cluster lane (c)
    int seg = (t >> 4) & 3;                // 16-lane segment within wave
    int wave = (b * 256 + t) >> 6;         // wave handles 32 edges
    int wbase = wave * 32;

    // coalesced index loads: 32 srcs + 32 dsts per wave via 2 lanes-wide loads
    int e0 = wbase + q, e1 = wbase + 16 + q;
    int es0 = (e0 < E) ? ei[e0] : 0;
    int ed0 = (e0 < E) ? ei[E + e0] : 0;
    int es1 = (e1 < E) ? ei[e1] : 0;
    int ed1 = (e1 < E) ? ei[E + e1] : 0;

    float acc = 0.0f;
    #pragma unroll
    for (int i = 0; i < 4; ++i) {
        int m = seg * 4 + i;
        int sN0 = __shfl(es0, m, 16), dN0 = __shfl(ed0, m, 16);
        int sN1 = __shfl(es1, m, 16), dN1 = __shfl(ed1, m, 16);
        float a0 = s[sN0 * NC + q];
        float b0 = ((wbase + m) < E) ? s[dN0 * NC + q] : 0.0f;
        float a1 = s[sN1 * NC + q];
        float b1 = ((wbase + 16 + m) < E) ? s[dN1 * NC + q] : 0.0f;
        acc = fmaf(a0, b0, acc);
        acc = fmaf(a1, b1, acc);
    }
    // full-wave reduce: sums the 16 components x 4 segments = 32 edge-dots
    #pragma unroll
    for (int o = 32; o; o >>= 1) acc += __shfl_xor(acc, o, 64);
    if ((t & 63) == 0) atomicAdd(&trb[(wave & 15) * 32], acc);
}

// ---------------- K6: sync-free epilogue (1 block, 4 waves, no LDS) ----------------
__device__ __forceinline__ float selu_f(float x) {
    const float a = 1.6732632423543772f, sc = 1.0507009873554805f;
    return sc * (x > 0.0f ? x : a * (expf(x) - 1.0f));
}

__global__ __launch_bounds__(256) void k_final(float* __restrict__ ws,
                                               float* __restrict__ d_out, float Ef) {
    float* oraw = ws + WS_ORAW;
    float* ssb  = ws + WS_SS;
    float* cab  = ws + WS_CA;
    float* csb  = ws + WS_CS;
    float* trb  = ws + WS_TR;
    int t = threadIdx.x;
    int lane = t & 63, w = t >> 6;

    if (w == 0) {
        float tot[4];
        float fr2 = 0.f;
        #pragma unroll
        for (int j = 0; j < 4; ++j) {
            int i = lane + j * 64;
            float v = ssb[i] + ssb[256 + i] + ssb[512 + i] + ssb[768 + i];
            tot[j] = v;
            fr2 += v * v;
        }
        #pragma unroll
        for (int o = 32; o; o >>= 1) fr2 += __shfl_xor(fr2, o, 64);
        float fro = sqrtf(fr2);
        float o2 = 0.f;
        #pragma unroll
        for (int j = 0; j < 4; ++j) {
            int i = lane + j * 64;
            float d = tot[j] / fro - ((i % 17 == 0) ? 0.25f : 0.f);
            o2 += d * d;
        }
        #pragma unroll
        for (int o = 32; o; o >>= 1) o2 += __shfl_xor(o2, o, 64);
        float ortho = sqrtf(o2);

        float tv = 0.f, ca = 0.f, cs = 0.f;
        if (lane < 16) {
            tv = trb[lane * 32];           // 16 trace replicas
            #pragma unroll
            for (int r = 0; r < 16; ++r) { ca += cab[r * 16 + lane]; cs += csb[r * 16 + lane]; }
        }
        float tr = tv, can = ca * ca, csn = cs * cs;
        #pragma unroll
        for (int o = 32; o; o >>= 1) {
            tr  += __shfl_xor(tr, o, 64);
            can += __shfl_xor(can, o, 64);
            csn += __shfl_xor(csn, o, 64);
        }
        float spectral = -(tr - can / Ef) / Ef;
        float cluster = sqrtf(csn) / (float)NN * 4.0f - 1.0f;
        if (lane == 0) d_out[NC * FH] = spectral + ortho + cluster;
    }

    #pragma unroll
    for (int rr = 0; rr < 4; ++rr) {
        int cR = w + rr * 4;
        int c0 = lane * 2;
        float va = 0.f, vb = 0.f;
        #pragma unroll
        for (int r = 0; r < 4; ++r) {
            float2 vv = *reinterpret_cast<const float2*>(&oraw[r * 2048 + cR * FH + c0]);
            va += vv.x;
            vb += vv.y;
        }
        va = selu_f(va);
        vb = selu_f(vb);
        float mx = fmaxf(va, vb);
        #pragma unroll
        for (int o = 32; o; o >>= 1) mx = fmaxf(mx, __shfl_xor(mx, o, 64));
        float sm = expf(va - mx) + expf(vb - mx);
        #pragma unroll
        for (int o = 32; o; o >>= 1) sm += __shfl_xor(sm, o, 64);
        float ls = mx + logf(sm);
        d_out[cR * FH + c0]     = va - ls;
        d_out[cR * FH + c0 + 1] = vb - ls;
    }
}

extern "C" void kernel_launch(void* const* d_in, const int* in_sizes, int n_in,
                              void* d_out, int out_size, void* d_ws, size_t ws_size,
                              hipStream_t stream) {
    const float* x  = (const float*)d_in[0];
    const float* W1 = (const float*)d_in[1];
    const float* b1 = (const float*)d_in[2];
    const float* Wp = (const float*)d_in[3];
    const float* bp = (const float*)d_in[4];
    const int*   ei = (const int*)d_in[5];
    int E = in_sizes[5] / 2;

    float* ws  = (float*)d_ws;
    float* out = (float*)d_out;           // [0..2047] log_softmax, [2048] loss
    float* s   = out + NC * FH + 1;       // [2049..] assignments (8192 x 16)

    k_zero_cnt<<<8, 256, 0, stream>>>((float4*)d_ws);
    k_degree  <<<(E + 255) / 256, 256, 0, stream>>>(ei, ws, E);
    k_edge_agg<<<(E + 255) / 256, 256, 0, stream>>>(ei, x, ws, E);
    k_node    <<<NN / CHUNK, 256, 0, stream>>>(x, W1, b1, Wp, bp, ws, s);
    k_adj     <<<ADJ_BLOCKS, 256, 0, stream>>>(ei, s, ws, E);
    k_final   <<<1, 256, 0, stream>>>(ws, out, (float)E);
}

// Round 18
// 66.152 us; speedup vs baseline: 1.0906x; 1.0249x over previous
//
#include <hip/hip_runtime.h>
#include <math.h>

#define NN 8192      // nodes
#define FH 128       // hidden
#define NC 16        // clusters
#define HP 132       // padded LDS row
#define CHUNK 32     // nodes per block in node phase (256 blocks)

// ---------------- workspace layout (floats) ----------------
#define WS_CNT   0          // [8192]   zeroed by k_zero_cnt
#define WS_AGG4  8192       // [32768]  zeroed by k_degree
// accumulator region zeroed by k_edge_agg (blocks 0-9):
#define WS_ORAW  40960      // 4 x 2048 replicas
#define WS_SS    49152      // 4 x 256 replicas
#define WS_CA    50176      // 16 x 16
#define WS_CS    50432      // 16 x 16
#define WS_TR    50688      // 16 replicas spread 32 floats (128B) apart
#define WS_END   51200
#define WS_ACC_BEGIN_F4 10240   // 40960/4
#define WS_ACC_COUNT_F4 2560    // (51200-40960)/4

// ---------------- K1: zero cnt only ----------------
__global__ __launch_bounds__(256) void k_zero_cnt(float4* __restrict__ ws) {
    int i = blockIdx.x * blockDim.x + threadIdx.x;   // 8 blocks
    if (i < NN / 4) ws[i] = make_float4(0.f, 0.f, 0.f, 0.f);
}

// ---------------- K2: in-degree (1 edge/thread, 1024x128) + zero agg4 ----------------
__global__ __launch_bounds__(128) void k_degree(const int* __restrict__ ei,
                                                float* __restrict__ ws, int E) {
    int t = threadIdx.x, b = blockIdx.x;             // 1024 blocks x 128
    if (t < 8)    // zero agg4: 1024 blocks x 8 f4 = 32768 floats
        reinterpret_cast<float4*>(ws)[NN / 4 + b * 8 + t] =
            make_float4(0.f, 0.f, 0.f, 0.f);
    int e = b * 128 + t;
    if (e < E) atomicAdd(&ws[WS_CNT + ei[E + e]], 1.0f);
}

// ---------------- K3: agg4 scatter (1 edge/thread, 1024x128) + zero accumulators ----------------
__global__ __launch_bounds__(128) void k_edge_agg(const int* __restrict__ ei,
                                                  const float* __restrict__ x,
                                                  float* __restrict__ ws, int E) {
    int t = threadIdx.x, b = blockIdx.x;             // 1024 blocks x 128
    if (b < 20) {   // zero oraw/ss/ca/cs/tr region (2560 f4)
        reinterpret_cast<float4*>(ws)[WS_ACC_BEGIN_F4 + b * 128 + t] =
            make_float4(0.f, 0.f, 0.f, 0.f);
    }
    int e = b * 128 + t;
    if (e >= E) return;
    int s = ei[e], d = ei[E + e];
    float di = rsqrtf(ws[WS_CNT + s] + 1.0f);
    float4 xv = reinterpret_cast<const float4*>(x)[s];
    float* agg4 = ws + WS_AGG4;
    atomicAdd(&agg4[d * 4 + 0], di * xv.x);
    atomicAdd(&agg4[d * 4 + 1], di * xv.y);
    atomicAdd(&agg4[d * 4 + 2], di * xv.z);
    atomicAdd(&agg4[d * 4 + 3], di * xv.w);
}

// ---------------- K4: fused node pipeline (32 nodes/block, 256 blocks) ----------------
__global__ __launch_bounds__(256) void k_node(const float* __restrict__ x,
                                              const float* __restrict__ W1,
                                              const float* __restrict__ b1,
                                              const float* __restrict__ Wp,
                                              const float* __restrict__ bp,
                                              float* __restrict__ ws,
                                              float* __restrict__ s_out) {
    float* cnt  = ws + WS_CNT;
    float* agg4 = ws + WS_AGG4;
    float* oraw = ws + WS_ORAW;
    float* ssb  = ws + WS_SS;
    float* cab  = ws + WS_CA;
    float* csb  = ws + WS_CS;

    __shared__ float h_lds[CHUNK][HP];
    __shared__ float wpT[NC * HP];
    __shared__ float s_lds[CHUNK][NC];
    __shared__ float z_lds[CHUNK][4];
    __shared__ float c_lds[CHUNK];
    int t = threadIdx.x;
    int b = blockIdx.x;
    int base = b * CHUNK;

    #pragma unroll
    for (int r = 0; r < 8; ++r) {
        int idx = r * 256 + t;             // = f*16 + c
        wpT[(idx & 15) * HP + (idx >> 4)] = Wp[idx];
    }
    if (t < CHUNK) {
        float4 a  = reinterpret_cast<const float4*>(agg4)[base + t];
        float4 xv = reinterpret_cast<const float4*>(x)[base + t];
        float cn = cnt[base + t];
        c_lds[t] = cn;
        float di = rsqrtf(cn + 1.0f);
        z_lds[t][0] = di * fmaf(xv.x, di, a.x);
        z_lds[t][1] = di * fmaf(xv.y, di, a.y);
        z_lds[t][2] = di * fmaf(xv.z, di, a.z);
        z_lds[t][3] = di * fmaf(xv.w, di, a.w);
    }
    __syncthreads();

    int f = t & 127;
    {
        float w0 = W1[f], w1 = W1[128 + f], w2 = W1[256 + f], w3 = W1[384 + f];
        float bb = b1[f];
        int n0 = t >> 7;
        #pragma unroll
        for (int r = 0; r < 16; ++r) {
            int n = n0 + r * 2;
            float v = fmaf(z_lds[n][0], w0, bb);
            v = fmaf(z_lds[n][1], w1, v);
            v = fmaf(z_lds[n][2], w2, v);
            v = fmaf(z_lds[n][3], w3, v);
            h_lds[n][f] = fmaxf(v, 0.0f);
        }
    }
    __syncthreads();

    int c = t & 15, g = t >> 4;
    const float4* wrow = reinterpret_cast<const float4*>(&wpT[c * HP]);
    #pragma unroll
    for (int pass = 0; pass < 2; ++pass) {
        int n = pass * 16 + g;
        const float4* hrow = reinterpret_cast<const float4*>(&h_lds[n][0]);
        float logit = bp[c];
        #pragma unroll 8
        for (int q = 0; q < 32; ++q) {
            float4 hv = hrow[q];
            float4 wv = wrow[q];
            logit = fmaf(hv.x, wv.x, logit);
            logit = fmaf(hv.y, wv.y, logit);
            logit = fmaf(hv.z, wv.z, logit);
            logit = fmaf(hv.w, wv.w, logit);
        }
        float m = logit;
        #pragma unroll
        for (int o = 8; o; o >>= 1) m = fmaxf(m, __shfl_xor(m, o, 16));
        float ex = expf(logit - m);
        float sum = ex;
        #pragma unroll
        for (int o = 8; o; o >>= 1) sum += __shfl_xor(sum, o, 16);
        float sv = ex / sum;
        s_lds[n][c] = sv;
        s_out[(base + n) * NC + c] = sv;   // single copy (d_out); k_adj gathers here
    }
    __syncthreads();

    float acc[8] = {0, 0, 0, 0, 0, 0, 0, 0};
    float acc_ss = 0.0f, acc_ca = 0.0f, acc_cs = 0.0f;
    int ch = t >> 7;
    int cS = t >> 4, kS = t & 15;
    #pragma unroll
    for (int i = 0; i < CHUNK; ++i) {
        float hv = h_lds[i][f];
        const float4* sv = reinterpret_cast<const float4*>(&s_lds[i][0]);
        float4 sa = sv[ch * 2], sb = sv[ch * 2 + 1];
        acc[0] = fmaf(sa.x, hv, acc[0]);
        acc[1] = fmaf(sa.y, hv, acc[1]);
        acc[2] = fmaf(sa.z, hv, acc[2]);
        acc[3] = fmaf(sa.w, hv, acc[3]);
        acc[4] = fmaf(sb.x, hv, acc[4]);
        acc[5] = fmaf(sb.y, hv, acc[5]);
        acc[6] = fmaf(sb.z, hv, acc[6]);
        acc[7] = fmaf(sb.w, hv, acc[7]);
        acc_ss = fmaf(s_lds[i][cS], s_lds[i][kS], acc_ss);
    }
    if (t < NC) {
        #pragma unroll
        for (int i = 0; i < CHUNK; ++i) {
            acc_ca = fmaf(s_lds[i][t], c_lds[i], acc_ca);
            acc_cs += s_lds[i][t];
        }
    }
    int rep = b & 3;
    #pragma unroll
    for (int j = 0; j < 8; ++j)
        atomicAdd(&oraw[rep * 2048 + (ch * 8 + j) * FH + f], acc[j]);
    atomicAdd(&ssb[rep * 256 + cS * NC + kS], acc_ss);
    if (t < NC) {
        int rep16 = b & 15;
        atomicAdd(&cab[rep16 * NC + t], acc_ca);
        atomicAdd(&csb[rep16 * NC + t], acc_cs);
    }
}

// ---------------- K5: TRACE-only adjacency, one edge per thread, float4 gathers ----------------
#define ADJ_BLOCKS 512
__global__ __launch_bounds__(256) void k_adj(const int* __restrict__ ei,
                                             const float* __restrict__ s,
                                             float* __restrict__ ws, int E) {
    float* trb = ws + WS_TR;

    int t = threadIdx.x;
    int b = blockIdx.x;
    int e = b * 256 + t;                   // one edge per thread

    float acc = 0.0f;
    if (e < E) {
        int sN = ei[e], dN = ei[E + e];
        const float4* sr = reinterpret_cast<const float4*>(&s[sN * NC]);
        const float4* dr = reinterpret_cast<const float4*>(&s[dN * NC]);
        // 8 independent 16B loads, all in flight
        float4 a0 = sr[0], a1 = sr[1], a2 = sr[2], a3 = sr[3];
        float4 b0 = dr[0], b1 = dr[1], b2 = dr[2], b3 = dr[3];
        acc = a0.x * b0.x + a0.y * b0.y + a0.z * b0.z + a0.w * b0.w;
        acc = fmaf(a1.x, b1.x, acc); acc = fmaf(a1.y, b1.y, acc);
        acc = fmaf(a1.z, b1.z, acc); acc = fmaf(a1.w, b1.w, acc);
        acc = fmaf(a2.x, b2.x, acc); acc = fmaf(a2.y, b2.y, acc);
        acc = fmaf(a2.z, b2.z, acc); acc = fmaf(a2.w, b2.w, acc);
        acc = fmaf(a3.x, b3.x, acc); acc = fmaf(a3.y, b3.y, acc);
        acc = fmaf(a3.z, b3.z, acc); acc = fmaf(a3.w, b3.w, acc);
    }
    // wave-reduce 64 edge-dots -> 1 atomic per wave
    #pragma unroll
    for (int o = 32; o; o >>= 1) acc += __shfl_xor(acc, o, 64);
    if ((t & 63) == 0) {
        int wave = (b * 256 + t) >> 6;
        atomicAdd(&trb[(wave & 15) * 32], acc);
    }
}

// ---------------- K6: sync-free epilogue (1 block, 4 waves, no LDS) ----------------
__device__ __forceinline__ float selu_f(float x) {
    const float a = 1.6732632423543772f, sc = 1.0507009873554805f;
    return sc * (x > 0.0f ? x : a * (expf(x) - 1.0f));
}

__global__ __launch_bounds__(256) void k_final(float* __restrict__ ws,
                                               float* __restrict__ d_out, float Ef) {
    float* oraw = ws + WS_ORAW;
    float* ssb  = ws + WS_SS;
    float* cab  = ws + WS_CA;
    float* csb  = ws + WS_CS;
    float* trb  = ws + WS_TR;
    int t = threadIdx.x;
    int lane = t & 63, w = t >> 6;

    if (w == 0) {
        float tot[4];
        float fr2 = 0.f;
        #pragma unroll
        for (int j = 0; j < 4; ++j) {
            int i = lane + j * 64;
            float v = ssb[i] + ssb[256 + i] + ssb[512 + i] + ssb[768 + i];
            tot[j] = v;
            fr2 += v * v;
        }
        #pragma unroll
        for (int o = 32; o; o >>= 1) fr2 += __shfl_xor(fr2, o, 64);
        float fro = sqrtf(fr2);
        float o2 = 0.f;
        #pragma unroll
        for (int j = 0; j < 4; ++j) {
            int i = lane + j * 64;
            float d = tot[j] / fro - ((i % 17 == 0) ? 0.25f : 0.f);
            o2 += d * d;
        }
        #pragma unroll
        for (int o = 32; o; o >>= 1) o2 += __shfl_xor(o2, o, 64);
        float ortho = sqrtf(o2);

        float tv = 0.f, ca = 0.f, cs = 0.f;
        if (lane < 16) {
            tv = trb[lane * 32];           // 16 trace replicas
            #pragma unroll
            for (int r = 0; r < 16; ++r) { ca += cab[r * 16 + lane]; cs += csb[r * 16 + lane]; }
        }
        float tr = tv, can = ca * ca, csn = cs * cs;
        #pragma unroll
        for (int o = 32; o; o >>= 1) {
            tr  += __shfl_xor(tr, o, 64);
            can += __shfl_xor(can, o, 64);
            csn += __shfl_xor(csn, o, 64);
        }
        float spectral = -(tr - can / Ef) / Ef;
        float cluster = sqrtf(csn) / (float)NN * 4.0f - 1.0f;
        if (lane == 0) d_out[NC * FH] = spectral + ortho + cluster;
    }

    #pragma unroll
    for (int rr = 0; rr < 4; ++rr) {
        int cR = w + rr * 4;
        int c0 = lane * 2;
        float va = 0.f, vb = 0.f;
        #pragma unroll
        for (int r = 0; r < 4; ++r) {
            float2 vv = *reinterpret_cast<const float2*>(&oraw[r * 2048 + cR * FH + c0]);
            va += vv.x;
            vb += vv.y;
        }
        va = selu_f(va);
        vb = selu_f(vb);
        float mx = fmaxf(va, vb);
        #pragma unroll
        for (int o = 32; o; o >>= 1) mx = fmaxf(mx, __shfl_xor(mx, o, 64));
        float sm = expf(va - mx) + expf(vb - mx);
        #pragma unroll
        for (int o = 32; o; o >>= 1) sm += __shfl_xor(sm, o, 64);
        float ls = mx + logf(sm);
        d_out[cR * FH + c0]     = va - ls;
        d_out[cR * FH + c0 + 1] = vb - ls;
    }
}

extern "C" void kernel_launch(void* const* d_in, const int* in_sizes, int n_in,
                              void* d_out, int out_size, void* d_ws, size_t ws_size,
                              hipStream_t stream) {
    const float* x  = (const float*)d_in[0];
    const float* W1 = (const float*)d_in[1];
    const float* b1 = (const float*)d_in[2];
    const float* Wp = (const float*)d_in[3];
    const float* bp = (const float*)d_in[4];
    const int*   ei = (const int*)d_in[5];
    int E = in_sizes[5] / 2;

    float* ws  = (float*)d_ws;
    float* out = (float*)d_out;           // [0..2047] log_softmax, [2048] loss
    float* s   = out + NC * FH + 1;       // [2049..] assignments (8192 x 16)

    k_zero_cnt<<<8, 256, 0, stream>>>((float4*)d_ws);
    k_degree  <<<(E + 127) / 128, 128, 0, stream>>>(ei, ws, E);
    k_edge_agg<<<(E + 127) / 128, 128, 0, stream>>>(ei, x, ws, E);
    k_node    <<<NN / CHUNK, 256, 0, stream>>>(x, W1, b1, Wp, bp, ws, s);
    k_adj     <<<(E + 255) / 256, 256, 0, stream>>>(ei, s, ws, E);
    k_final   <<<1, 256, 0, stream>>>(ws, out, (float)E);
}